// Round 4
// baseline (356.661 us; speedup 1.0000x reference)
//
#include <hip/hip_runtime.h>
#include <math.h>

#define CHUNK 8192
#define BSH 8            // bucket shift: 256 nodes per bucket
#define BNODES 256
#define CAP 12288        // LDS stage capacity per bucket (avg 8184, sigma ~90)

// Workspace layout (4-byte units):
//   dinv  : N            rsqrt(1+deg)
//   ptrS  : N+1          CSR row starts (ptrS[N] = E)
//   tot   : nb           per-bucket edge totals
//   base  : nb+1         exclusive bucket bases (base[nb] = E)
//   off   : (nb+1)*NBLK  ushort per-(bucket,chunk) exclusive offsets
//   csr   : E            source nodes grouped by destination
//   tempU : max(E,32N)   binned packed edges; after k_build aliased by feature
//                        planes: h0pA|h0pB|h1pA|h1pB (8N each). a2A/a2B alias
//                        h0pA/h0pB (dead after layer-1 passes).
//   g     : 16G          pooled graph accumulator

__global__ void k_init(int* tot, float* g, int nb, int G16) {
    int i = blockIdx.x * blockDim.x + threadIdx.x;
    if (i < nb)  tot[i] = 0;
    if (i < G16) g[i]   = 0.0f;
}

// Phase 1: bin this block's 8192-edge chunk by destination bucket.
// All scattered writes staged in LDS; temp written back as full coalesced lines.
__global__ void k_bin(const int* __restrict__ row, const int* __restrict__ col,
                      int* __restrict__ temp, unsigned short* __restrict__ off,
                      int* __restrict__ tot, int E, int NBLK, int nb) {
    __shared__ int cnt[512];
    __shared__ int cur[512];
    __shared__ int sc[512];
    __shared__ int stage[CHUNK];
    int blk = blockIdx.x;
    int start = blk * CHUNK;
    int cs = E - start; if (cs > CHUNK) cs = CHUNK;
    int t = threadIdx.x;     // 512 threads
    cnt[t] = 0;
    __syncthreads();
    for (int i = t; i < cs; i += 512) atomicAdd(&cnt[col[start + i] >> BSH], 1);
    __syncthreads();
    int c = cnt[t];
    sc[t] = c;
    __syncthreads();
    for (int o = 1; o < 512; o <<= 1) {
        int x = (t >= o) ? sc[t - o] : 0;
        __syncthreads();
        sc[t] += x;
        __syncthreads();
    }
    int excl = sc[t] - c;
    if (t < nb) {
        off[t * NBLK + blk] = (unsigned short)excl;
        if (c) atomicAdd(&tot[t], c);
    }
    if (t == 0) off[nb * NBLK + blk] = (unsigned short)cs;
    cur[t] = excl;
    __syncthreads();
    for (int i = t; i < cs; i += 512) {
        int cc = col[start + i];
        int rr = row[start + i];
        int p = atomicAdd(&cur[cc >> BSH], 1);
        stage[p] = (rr << BSH) | (cc & (BNODES - 1));
    }
    __syncthreads();
    for (int i = t; i < cs; i += 512) temp[start + i] = stage[i];
}

// exclusive scan of bucket totals -> base (carry loop); sentinels.
__global__ void k_base(const int* __restrict__ tot, int* __restrict__ base,
                       int* __restrict__ ptrS, int E, int nb, int N) {
    __shared__ int s[512];
    __shared__ int carry;
    int t = threadIdx.x;
    if (t == 0) carry = 0;
    __syncthreads();
    for (int b0 = 0; b0 < nb; b0 += 512) {
        int i = b0 + t;
        int v = (i < nb) ? tot[i] : 0;
        s[t] = v;
        __syncthreads();
        for (int o = 1; o < 512; o <<= 1) {
            int x = (t >= o) ? s[t - o] : 0;
            __syncthreads();
            s[t] += x;
            __syncthreads();
        }
        if (i < nb) base[i] = s[t] - v + carry;
        __syncthreads();
        if (t == 0) carry += s[511];
        __syncthreads();
    }
    if (t == 0) { base[nb] = E; ptrS[N] = E; }
}

// Phase 2: one block per 256-node bucket. LDS histogram + scan, then scatter the
// bucket's csr window into an LDS stage and write back fully coalesced.
__global__ void k_build(const int* __restrict__ temp, const unsigned short* __restrict__ off,
                        const int* __restrict__ base, int* __restrict__ ptrS,
                        float* __restrict__ dinv, int* __restrict__ csr,
                        int NBLK, int N) {
    __shared__ int cnt[BNODES];
    __shared__ int cur[BNODES];
    __shared__ int sc[BNODES];
    __shared__ int stage[CAP];
    int b = blockIdx.x;
    int t = threadIdx.x;     // 512 threads
    if (t < BNODES) cnt[t] = 0;
    __syncthreads();
    for (int seg = t; seg < NBLK; seg += 512) {
        int s0 = off[b * NBLK + seg];
        int s1 = off[(b + 1) * NBLK + seg];
        int sb = seg * CHUNK;
        for (int i = s0; i < s1; ++i)
            atomicAdd(&cnt[temp[sb + i] & (BNODES - 1)], 1);
    }
    __syncthreads();
    if (t < BNODES) sc[t] = cnt[t];
    __syncthreads();
    for (int o = 1; o < BNODES; o <<= 1) {
        int x = 0;
        if (t < BNODES && t >= o) x = sc[t - o];
        __syncthreads();
        if (t < BNODES) sc[t] += x;
        __syncthreads();
    }
    int bb = base[b];
    if (t < BNODES) {
        int c = cnt[t];
        int startp = bb + sc[t] - c;
        int node = (b << BSH) + t;
        if (node < N) {
            ptrS[node] = startp;
            dinv[node] = rsqrtf(1.0f + (float)c);
        }
        cur[t] = startp;
    }
    __syncthreads();
    for (int seg = t; seg < NBLK; seg += 512) {
        int s0 = off[b * NBLK + seg];
        int s1 = off[(b + 1) * NBLK + seg];
        int sb = seg * CHUNK;
        for (int i = s0; i < s1; ++i) {
            int e = temp[sb + i];
            int p = atomicAdd(&cur[e & (BNODES - 1)], 1);
            int loc = p - bb;
            int r = e >> BSH;
            if (loc < CAP) stage[loc] = r;
            else           csr[p] = r;     // statistically unreachable overflow
        }
    }
    __syncthreads();
    int total = base[b + 1] - bb;
    if (total > CAP) total = CAP;
    for (int i = t; i < total; i += 512) csr[bb + i] = stage[i];
}

// h0p planes: h0pA[v][k] (k=0..7), h0pB[v][k-8] = dinv[v] * (x @ W1)[v][k]
__global__ void k_xw1(const float* __restrict__ x, const float* __restrict__ W1,
                      const float* __restrict__ dinv, float* __restrict__ h0pA,
                      float* __restrict__ h0pB, int N) {
    int t = blockIdx.x * blockDim.x + threadIdx.x;
    if (t >= N * 16) return;
    int v = t >> 4, k = t & 15;
    float x0 = x[v * 3 + 0], x1 = x[v * 3 + 1], x2 = x[v * 3 + 2];
    float val = dinv[v] * (x0 * W1[k] + x1 * W1[16 + k] + x2 * W1[32 + k]);
    if (k < 8) h0pA[v * 8 + k] = val;
    else       h0pB[v * 8 + (k - 8)] = val;
}

// Layer-1 half-feature gather: src plane (3.2MB, L2-resident) random reads;
// csr/output use non-temporal so they don't evict the plane from L2.
// out = dinv[v] * relu(dinv[v]*(acc + self) + b1p[k])
__global__ void k_g1(const int* __restrict__ ptrS, const int* __restrict__ csr,
                     const float* __restrict__ dinv, const float* __restrict__ src,
                     const float* __restrict__ b1p, float* __restrict__ dst, int N) {
    int t = blockIdx.x * blockDim.x + threadIdx.x;
    int v = t >> 3, k = t & 7;
    if (v >= N) return;
    int s = ptrS[v], e = ptrS[v + 1];
    float a0 = 0.0f, a1 = 0.0f, a2 = 0.0f, a3 = 0.0f;
    int i = s;
    for (; i + 3 < e; i += 4) {
        int r0 = __builtin_nontemporal_load(csr + i);
        int r1 = __builtin_nontemporal_load(csr + i + 1);
        int r2 = __builtin_nontemporal_load(csr + i + 2);
        int r3 = __builtin_nontemporal_load(csr + i + 3);
        a0 += src[r0 * 8 + k];
        a1 += src[r1 * 8 + k];
        a2 += src[r2 * 8 + k];
        a3 += src[r3 * 8 + k];
    }
    for (; i < e; ++i) a0 += src[__builtin_nontemporal_load(csr + i) * 8 + k];
    float d = dinv[v];
    float z = d * ((a0 + a1) + (a2 + a3) + src[v * 8 + k]) + b1p[k];
    __builtin_nontemporal_store(d * fmaxf(z, 0.0f), dst + v * 8 + k);
}

// Layer-2 half-feature gather (no bias/relu; W2 deferred to k_final):
// out = dinv[v] * (acc + self)
__global__ void k_g2(const int* __restrict__ ptrS, const int* __restrict__ csr,
                     const float* __restrict__ dinv, const float* __restrict__ src,
                     float* __restrict__ dst, int N) {
    int t = blockIdx.x * blockDim.x + threadIdx.x;
    int v = t >> 3, k = t & 7;
    if (v >= N) return;
    int s = ptrS[v], e = ptrS[v + 1];
    float a0 = 0.0f, a1 = 0.0f, a2 = 0.0f, a3 = 0.0f;
    int i = s;
    for (; i + 3 < e; i += 4) {
        int r0 = __builtin_nontemporal_load(csr + i);
        int r1 = __builtin_nontemporal_load(csr + i + 1);
        int r2 = __builtin_nontemporal_load(csr + i + 2);
        int r3 = __builtin_nontemporal_load(csr + i + 3);
        a0 += src[r0 * 8 + k];
        a1 += src[r1 * 8 + k];
        a2 += src[r2 * 8 + k];
        a3 += src[r3 * 8 + k];
    }
    for (; i < e; ++i) a0 += src[__builtin_nontemporal_load(csr + i) * 8 + k];
    float d = dinv[v];
    __builtin_nontemporal_store(d * ((a0 + a1) + (a2 + a3) + src[v * 8 + k]),
                                dst + v * 8 + k);
}

// Epilogue: z2 = a2 @ W2 + b2 (a2 = A_hat·h1, planes A/B), then pool by graph
// with wave-level pre-reduction. Sequential reads, tiny kernel.
__global__ void k_final(const float* __restrict__ a2A, const float* __restrict__ a2B,
                        const float* __restrict__ W2, const float* __restrict__ b2,
                        const int* __restrict__ batch, float* __restrict__ g, int N) {
    __shared__ float sW[256];
    sW[threadIdx.x] = W2[threadIdx.x];
    __syncthreads();
    int t = blockIdx.x * blockDim.x + threadIdx.x;
    int v = t >> 4, k = t & 15;
    bool valid = (v < N);
    float val = 0.0f;
    int bg = 0;
    if (valid) {
        float mine = (k < 8) ? a2A[v * 8 + k] : a2B[v * 8 + (k & 7)];
        float o = 0.0f;
#pragma unroll
        for (int j = 0; j < 16; ++j) o += __shfl(mine, j, 16) * sW[j * 16 + k];
        val = o + b2[k];
        bg = batch[v];
    }
    int lane = threadIdx.x & 63;
    int bg0 = __shfl(bg, lane & 15, 64);
    bool uni = __all(valid && (bg == bg0));
    if (uni) {
        val += __shfl_xor(val, 16, 64);
        val += __shfl_xor(val, 32, 64);
        if (lane < 16) atomicAdd(&g[bg * 16 + k], val);
    } else if (valid) {
        atomicAdd(&g[bg * 16 + k], val);
    }
}

// logits = g @ Wl + bl (16x7), then log_softmax over 7. One thread per graph.
__global__ void k_head(const float* __restrict__ g, const float* __restrict__ Wl,
                       const float* __restrict__ bl, float* __restrict__ out, int G) {
    int gi = blockIdx.x * blockDim.x + threadIdx.x;
    if (gi >= G) return;
    float gv[16];
#pragma unroll
    for (int k = 0; k < 16; ++k) gv[k] = g[gi * 16 + k];
    float lo[7];
    float mx = -1e30f;
#pragma unroll
    for (int j = 0; j < 7; ++j) {
        float a = bl[j];
#pragma unroll
        for (int k = 0; k < 16; ++k) a += gv[k] * Wl[k * 7 + j];
        lo[j] = a;
        mx = fmaxf(mx, a);
    }
    float s = 0.0f;
#pragma unroll
    for (int j = 0; j < 7; ++j) s += expf(lo[j] - mx);
    float lse = mx + logf(s);
#pragma unroll
    for (int j = 0; j < 7; ++j) out[gi * 7 + j] = lo[j] - lse;
}

extern "C" void kernel_launch(void* const* d_in, const int* in_sizes, int n_in,
                              void* d_out, int out_size, void* d_ws, size_t ws_size,
                              hipStream_t stream) {
    const float* x    = (const float*)d_in[0];
    const int*   ei   = (const int*)d_in[1];   // [2, E]: row = ei[0:E), col = ei[E:2E)
    const int*   batch = (const int*)d_in[3];
    const float* W1 = (const float*)d_in[4];
    const float* b1 = (const float*)d_in[5];
    const float* W2 = (const float*)d_in[6];
    const float* b2 = (const float*)d_in[7];
    const float* Wl = (const float*)d_in[8];
    const float* bl = (const float*)d_in[9];
    float* out = (float*)d_out;

    const int N = in_sizes[0] / 3;
    const int E = in_sizes[1] / 2;
    const int G = out_size / 7;

    const int* row = ei;
    const int* col = ei + E;

    const int NBLK = (E + CHUNK - 1) / CHUNK;
    const int nb   = (N + BNODES - 1) >> BSH;

    int* w = (int*)d_ws;
    float* dinv = (float*)w;            w += N;
    int*   ptrS = w;                    w += N + 1;
    int*   tot  = w;                    w += nb;
    int*   base = w;                    w += nb + 1;
    unsigned short* off = (unsigned short*)w;
    w += ((nb + 1) * NBLK + 1) / 2;     // ushort table, rounded up to int units
    int*   csr  = w;                    w += E;
    int tempsz = E > 32 * N ? E : 32 * N;
    int*   temp = w;                    w += tempsz;
    // feature planes alias temp (dead after k_build); a2 planes alias h0p planes
    float* h0pA = (float*)temp;
    float* h0pB = h0pA + 8 * N;
    float* h1pA = h0pB + 8 * N;
    float* h1pB = h1pA + 8 * N;
    float* a2A  = h0pA;                 // h0p dead after layer-1 passes
    float* a2B  = h0pB;
    float* g    = (float*)w;            w += 16 * G;

    const int TB = 256;
    const int n16 = N * 16;
    const int n8  = N * 8;
    const int G16 = G * 16;
    const int initn = (G16 > nb) ? G16 : nb;

    k_init<<<(initn + TB - 1) / TB, TB, 0, stream>>>(tot, g, nb, G16);
    k_bin<<<NBLK, 512, 0, stream>>>(row, col, temp, off, tot, E, NBLK, nb);
    k_base<<<1, 512, 0, stream>>>(tot, base, ptrS, E, nb, N);
    k_build<<<nb, 512, 0, stream>>>(temp, off, base, ptrS, dinv, csr, NBLK, N);
    k_xw1<<<(n16 + TB - 1) / TB, TB, 0, stream>>>(x, W1, dinv, h0pA, h0pB, N);
    k_g1<<<(n8 + TB - 1) / TB, TB, 0, stream>>>(ptrS, csr, dinv, h0pA, b1,     h1pA, N);
    k_g1<<<(n8 + TB - 1) / TB, TB, 0, stream>>>(ptrS, csr, dinv, h0pB, b1 + 8, h1pB, N);
    k_g2<<<(n8 + TB - 1) / TB, TB, 0, stream>>>(ptrS, csr, dinv, h1pA, a2A, N);
    k_g2<<<(n8 + TB - 1) / TB, TB, 0, stream>>>(ptrS, csr, dinv, h1pB, a2B, N);
    k_final<<<(n16 + TB - 1) / TB, TB, 0, stream>>>(a2A, a2B, W2, b2, batch, g, N);
    k_head<<<(G + TB - 1) / TB, TB, 0, stream>>>(g, Wl, bl, out, G);
}

// Round 5
// 251.681 us; speedup vs baseline: 1.4171x; 1.4171x over previous
//
#include <hip/hip_runtime.h>
#include <math.h>

#define CHUNK 8192
#define BSH 8            // bucket shift: 256 nodes per bucket
#define BNODES 256
#define CAP 12288        // LDS stage capacity per bucket (avg 8184, sigma ~90)

// Workspace layout (4-byte units):
//   dinv  : N            rsqrt(1+deg)
//   ptrS  : N+1          CSR row starts (ptrS[N] = E)
//   tot   : nb           per-bucket edge totals
//   base  : nb+1         exclusive bucket bases (base[nb] = E)
//   off   : (nb+1)*NBLK  ushort per-(bucket,chunk) exclusive offsets
//   csr   : E            source nodes grouped by destination
//   tempU : max(E,32N)   binned packed edges; after k_build aliased by fp16
//                        feature tables h0h (16N halves = 8N ints) + h1h (8N ints)
//   g     : 16G          pooled graph accumulator

__global__ void k_init(int* tot, float* g, int nb, int G16) {
    int i = blockIdx.x * blockDim.x + threadIdx.x;
    if (i < nb)  tot[i] = 0;
    if (i < G16) g[i]   = 0.0f;
}

// Phase 1: bin this block's 8192-edge chunk by destination bucket.
// All scattered writes staged in LDS; temp written back as full coalesced lines.
__global__ void k_bin(const int* __restrict__ row, const int* __restrict__ col,
                      int* __restrict__ temp, unsigned short* __restrict__ off,
                      int* __restrict__ tot, int E, int NBLK, int nb) {
    __shared__ int cnt[512];
    __shared__ int cur[512];
    __shared__ int sc[512];
    __shared__ int stage[CHUNK];
    int blk = blockIdx.x;
    int start = blk * CHUNK;
    int cs = E - start; if (cs > CHUNK) cs = CHUNK;
    int t = threadIdx.x;     // 512 threads
    cnt[t] = 0;
    __syncthreads();
    for (int i = t; i < cs; i += 512) atomicAdd(&cnt[col[start + i] >> BSH], 1);
    __syncthreads();
    int c = cnt[t];
    sc[t] = c;
    __syncthreads();
    for (int o = 1; o < 512; o <<= 1) {
        int x = (t >= o) ? sc[t - o] : 0;
        __syncthreads();
        sc[t] += x;
        __syncthreads();
    }
    int excl = sc[t] - c;
    if (t < nb) {
        off[t * NBLK + blk] = (unsigned short)excl;
        if (c) atomicAdd(&tot[t], c);
    }
    if (t == 0) off[nb * NBLK + blk] = (unsigned short)cs;
    cur[t] = excl;
    __syncthreads();
    for (int i = t; i < cs; i += 512) {
        int cc = col[start + i];
        int rr = row[start + i];
        int p = atomicAdd(&cur[cc >> BSH], 1);
        stage[p] = (rr << BSH) | (cc & (BNODES - 1));
    }
    __syncthreads();
    for (int i = t; i < cs; i += 512) temp[start + i] = stage[i];
}

// exclusive scan of bucket totals -> base (carry loop); sentinels.
__global__ void k_base(const int* __restrict__ tot, int* __restrict__ base,
                       int* __restrict__ ptrS, int E, int nb, int N) {
    __shared__ int s[512];
    __shared__ int carry;
    int t = threadIdx.x;
    if (t == 0) carry = 0;
    __syncthreads();
    for (int b0 = 0; b0 < nb; b0 += 512) {
        int i = b0 + t;
        int v = (i < nb) ? tot[i] : 0;
        s[t] = v;
        __syncthreads();
        for (int o = 1; o < 512; o <<= 1) {
            int x = (t >= o) ? s[t - o] : 0;
            __syncthreads();
            s[t] += x;
            __syncthreads();
        }
        if (i < nb) base[i] = s[t] - v + carry;
        __syncthreads();
        if (t == 0) carry += s[511];
        __syncthreads();
    }
    if (t == 0) { base[nb] = E; ptrS[N] = E; }
}

// Phase 2: one block per 256-node bucket. LDS histogram + scan, then scatter the
// bucket's csr window into an LDS stage and write back fully coalesced.
__global__ void k_build(const int* __restrict__ temp, const unsigned short* __restrict__ off,
                        const int* __restrict__ base, int* __restrict__ ptrS,
                        float* __restrict__ dinv, int* __restrict__ csr,
                        int NBLK, int N) {
    __shared__ int cnt[BNODES];
    __shared__ int cur[BNODES];
    __shared__ int sc[BNODES];
    __shared__ int stage[CAP];
    int b = blockIdx.x;
    int t = threadIdx.x;     // 512 threads
    if (t < BNODES) cnt[t] = 0;
    __syncthreads();
    for (int seg = t; seg < NBLK; seg += 512) {
        int s0 = off[b * NBLK + seg];
        int s1 = off[(b + 1) * NBLK + seg];
        int sb = seg * CHUNK;
        for (int i = s0; i < s1; ++i)
            atomicAdd(&cnt[temp[sb + i] & (BNODES - 1)], 1);
    }
    __syncthreads();
    if (t < BNODES) sc[t] = cnt[t];
    __syncthreads();
    for (int o = 1; o < BNODES; o <<= 1) {
        int x = 0;
        if (t < BNODES && t >= o) x = sc[t - o];
        __syncthreads();
        if (t < BNODES) sc[t] += x;
        __syncthreads();
    }
    int bb = base[b];
    if (t < BNODES) {
        int c = cnt[t];
        int startp = bb + sc[t] - c;
        int node = (b << BSH) + t;
        if (node < N) {
            ptrS[node] = startp;
            dinv[node] = rsqrtf(1.0f + (float)c);
        }
        cur[t] = startp;
    }
    __syncthreads();
    for (int seg = t; seg < NBLK; seg += 512) {
        int s0 = off[b * NBLK + seg];
        int s1 = off[(b + 1) * NBLK + seg];
        int sb = seg * CHUNK;
        for (int i = s0; i < s1; ++i) {
            int e = temp[sb + i];
            int p = atomicAdd(&cur[e & (BNODES - 1)], 1);
            int loc = p - bb;
            int r = e >> BSH;
            if (loc < CAP) stage[loc] = r;
            else           csr[p] = r;     // statistically unreachable overflow
        }
    }
    __syncthreads();
    int total = base[b + 1] - bb;
    if (total > CAP) total = CAP;
    for (int i = t; i < total; i += 512) csr[bb + i] = stage[i];
}

// h0h[v][k] = fp16( dinv[v] * (x @ W1)[v][k] )   (premultiplied, fp16 table)
__global__ void k_xw1(const float* __restrict__ x, const float* __restrict__ W1,
                      const float* __restrict__ dinv, _Float16* __restrict__ h0h, int N) {
    int t = blockIdx.x * blockDim.x + threadIdx.x;
    if (t >= N * 16) return;
    int v = t >> 4, k = t & 15;
    float x0 = x[v * 3 + 0], x1 = x[v * 3 + 1], x2 = x[v * 3 + 2];
    h0h[t] = (_Float16)(dinv[v] * (x0 * W1[k] + x1 * W1[16 + k] + x2 * W1[32 + k]));
}

// layer 1 gather over fp16 table (32B/row, L2-resident) + relu + W2 via shfl.
// Accumulation in f32. Writes h1h = fp16( dinv[v] * (h1 @ W2) ).
__global__ void k_gather1(const int* __restrict__ ptrS, const int* __restrict__ csr,
                          const float* __restrict__ dinv, const _Float16* __restrict__ h0h,
                          const float* __restrict__ W2, const float* __restrict__ b1,
                          _Float16* __restrict__ h1h, int N) {
    __shared__ float sW[256];
    sW[threadIdx.x] = W2[threadIdx.x];
    __syncthreads();
    int t = blockIdx.x * blockDim.x + threadIdx.x;
    int v = t >> 4, k = t & 15;
    if (v < N) {
        int s = ptrS[v], e = ptrS[v + 1];
        float a0 = 0.0f, a1 = 0.0f, a2 = 0.0f, a3 = 0.0f;
        int i = s;
        for (; i + 3 < e; i += 4) {
            int r0 = csr[i], r1 = csr[i + 1], r2 = csr[i + 2], r3 = csr[i + 3];
            a0 += (float)h0h[r0 * 16 + k];
            a1 += (float)h0h[r1 * 16 + k];
            a2 += (float)h0h[r2 * 16 + k];
            a3 += (float)h0h[r3 * 16 + k];
        }
        for (; i < e; ++i) a0 += (float)h0h[csr[i] * 16 + k];
        float d = dinv[v];
        float h = fmaxf(d * ((a0 + a1) + (a2 + a3) + (float)h0h[v * 16 + k]) + b1[k], 0.0f);
        float o = 0.0f;
#pragma unroll
        for (int j = 0; j < 16; ++j) o += __shfl(h, j, 16) * sW[j * 16 + k];
        h1h[v * 16 + k] = (_Float16)(d * o);
    }
}

// layer 2 gather over fp16 table + bias + pool with wave-level pre-reduction.
__global__ void k_gather2(const int* __restrict__ ptrS, const int* __restrict__ csr,
                          const float* __restrict__ dinv, const _Float16* __restrict__ h1h,
                          const float* __restrict__ b2, const int* __restrict__ batch,
                          float* __restrict__ g, int N) {
    int t = blockIdx.x * blockDim.x + threadIdx.x;
    int v = t >> 4, k = t & 15;
    bool valid = (v < N);
    float val = 0.0f;
    int bg = 0;
    if (valid) {
        int s = ptrS[v], e = ptrS[v + 1];
        float a0 = 0.0f, a1 = 0.0f, a2 = 0.0f, a3 = 0.0f;
        int i = s;
        for (; i + 3 < e; i += 4) {
            int r0 = csr[i], r1 = csr[i + 1], r2 = csr[i + 2], r3 = csr[i + 3];
            a0 += (float)h1h[r0 * 16 + k];
            a1 += (float)h1h[r1 * 16 + k];
            a2 += (float)h1h[r2 * 16 + k];
            a3 += (float)h1h[r3 * 16 + k];
        }
        for (; i < e; ++i) a0 += (float)h1h[csr[i] * 16 + k];
        float d = dinv[v];
        val = d * ((a0 + a1) + (a2 + a3) + (float)h1h[v * 16 + k]) + b2[k];
        bg = batch[v];
    }
    int lane = threadIdx.x & 63;
    int bg0 = __shfl(bg, lane & 15, 64);
    bool uni = __all(valid && (bg == bg0));
    if (uni) {
        val += __shfl_xor(val, 16, 64);
        val += __shfl_xor(val, 32, 64);
        if (lane < 16) atomicAdd(&g[bg * 16 + k], val);
    } else if (valid) {
        atomicAdd(&g[bg * 16 + k], val);
    }
}

// logits = g @ Wl + bl (16x7), then log_softmax over 7. One thread per graph.
__global__ void k_head(const float* __restrict__ g, const float* __restrict__ Wl,
                       const float* __restrict__ bl, float* __restrict__ out, int G) {
    int gi = blockIdx.x * blockDim.x + threadIdx.x;
    if (gi >= G) return;
    float gv[16];
#pragma unroll
    for (int k = 0; k < 16; ++k) gv[k] = g[gi * 16 + k];
    float lo[7];
    float mx = -1e30f;
#pragma unroll
    for (int j = 0; j < 7; ++j) {
        float a = bl[j];
#pragma unroll
        for (int k = 0; k < 16; ++k) a += gv[k] * Wl[k * 7 + j];
        lo[j] = a;
        mx = fmaxf(mx, a);
    }
    float s = 0.0f;
#pragma unroll
    for (int j = 0; j < 7; ++j) s += expf(lo[j] - mx);
    float lse = mx + logf(s);
#pragma unroll
    for (int j = 0; j < 7; ++j) out[gi * 7 + j] = lo[j] - lse;
}

extern "C" void kernel_launch(void* const* d_in, const int* in_sizes, int n_in,
                              void* d_out, int out_size, void* d_ws, size_t ws_size,
                              hipStream_t stream) {
    const float* x    = (const float*)d_in[0];
    const int*   ei   = (const int*)d_in[1];   // [2, E]: row = ei[0:E), col = ei[E:2E)
    const int*   batch = (const int*)d_in[3];
    const float* W1 = (const float*)d_in[4];
    const float* b1 = (const float*)d_in[5];
    const float* W2 = (const float*)d_in[6];
    const float* b2 = (const float*)d_in[7];
    const float* Wl = (const float*)d_in[8];
    const float* bl = (const float*)d_in[9];
    float* out = (float*)d_out;

    const int N = in_sizes[0] / 3;
    const int E = in_sizes[1] / 2;
    const int G = out_size / 7;

    const int* row = ei;
    const int* col = ei + E;

    const int NBLK = (E + CHUNK - 1) / CHUNK;
    const int nb   = (N + BNODES - 1) >> BSH;

    int* w = (int*)d_ws;
    float* dinv = (float*)w;            w += N;
    int*   ptrS = w;                    w += N + 1;
    int*   tot  = w;                    w += nb;
    int*   base = w;                    w += nb + 1;
    unsigned short* off = (unsigned short*)w;
    w += ((nb + 1) * NBLK + 1) / 2;     // ushort table, rounded up to int units
    int*   csr  = w;                    w += E;
    int tempsz = E > 32 * N ? E : 32 * N;
    int*   temp = w;                    w += tempsz;
    // fp16 feature tables alias temp (dead after k_build)
    _Float16* h0h = (_Float16*)temp;             // 16N halves = 8N ints
    _Float16* h1h = (_Float16*)(temp + 8 * N);   // 16N halves = 8N ints
    float* g    = (float*)w;            w += 16 * G;

    const int TB = 256;
    const int n16 = N * 16;
    const int G16 = G * 16;
    const int initn = (G16 > nb) ? G16 : nb;

    k_init<<<(initn + TB - 1) / TB, TB, 0, stream>>>(tot, g, nb, G16);
    k_bin<<<NBLK, 512, 0, stream>>>(row, col, temp, off, tot, E, NBLK, nb);
    k_base<<<1, 512, 0, stream>>>(tot, base, ptrS, E, nb, N);
    k_build<<<nb, 512, 0, stream>>>(temp, off, base, ptrS, dinv, csr, NBLK, N);
    k_xw1<<<(n16 + TB - 1) / TB, TB, 0, stream>>>(x, W1, dinv, h0h, N);
    k_gather1<<<(n16 + TB - 1) / TB, TB, 0, stream>>>(ptrS, csr, dinv, h0h, W2, b1, h1h, N);
    k_gather2<<<(n16 + TB - 1) / TB, TB, 0, stream>>>(ptrS, csr, dinv, h1h, b2, batch, g, N);
    k_head<<<(G + TB - 1) / TB, TB, 0, stream>>>(g, Wl, bl, out, G);
}

// Round 6
// 243.313 us; speedup vs baseline: 1.4659x; 1.0344x over previous
//
#include <hip/hip_runtime.h>
#include <math.h>

#define CHUNK 8192
#define BSH 8            // bucket shift: 256 nodes per bucket
#define BNODES 256
#define RAWCAP 9216      // LDS edge capacity per bucket (avg 8192, sigma ~90 -> +11 sigma)
#define MAXCELL 512      // max chunks supported (E <= 4.19M)

// Workspace layout (4-byte units):
//   dinv  : N            rsqrt(1+deg)
//   ptrS  : N+1          CSR row starts (ptrS[N] = E)
//   tot   : nb           per-bucket edge totals
//   base  : nb+1         exclusive bucket bases (base[nb] = E)
//   off   : (nb+1)*NBLK  ushort per-(bucket,chunk) exclusive offsets
//   csr   : E            source nodes grouped by destination
//   tempU : max(E,32N)   binned packed edges; after k_build aliased by fp16
//                        feature tables h0h (16N halves = 8N ints) + h1h (8N ints)
//   g     : 16G          pooled graph accumulator

__global__ void k_init(int* tot, float* g, int nb, int G16) {
    int i = blockIdx.x * blockDim.x + threadIdx.x;
    if (i < nb)  tot[i] = 0;
    if (i < G16) g[i]   = 0.0f;
}

// Phase 1: bin this block's 8192-edge chunk by destination bucket.
// All scattered writes staged in LDS; temp written back as full coalesced lines.
__global__ __launch_bounds__(512) void k_bin(
                      const int* __restrict__ row, const int* __restrict__ col,
                      int* __restrict__ temp, unsigned short* __restrict__ off,
                      int* __restrict__ tot, int E, int NBLK, int nb) {
    __shared__ int cnt[512];
    __shared__ int cur[512];
    __shared__ int sc[512];
    __shared__ int stage[CHUNK];
    int blk = blockIdx.x;
    int start = blk * CHUNK;
    int cs = E - start; if (cs > CHUNK) cs = CHUNK;
    int t = threadIdx.x;     // 512 threads
    cnt[t] = 0;
    __syncthreads();
    for (int i = t; i < cs; i += 512) atomicAdd(&cnt[col[start + i] >> BSH], 1);
    __syncthreads();
    int c = cnt[t];
    sc[t] = c;
    __syncthreads();
    for (int o = 1; o < 512; o <<= 1) {
        int x = (t >= o) ? sc[t - o] : 0;
        __syncthreads();
        sc[t] += x;
        __syncthreads();
    }
    int excl = sc[t] - c;
    if (t < nb) {
        off[t * NBLK + blk] = (unsigned short)excl;
        if (c) atomicAdd(&tot[t], c);
    }
    if (t == 0) off[nb * NBLK + blk] = (unsigned short)cs;
    cur[t] = excl;
    __syncthreads();
    for (int i = t; i < cs; i += 512) {
        int cc = col[start + i];
        int rr = row[start + i];
        int p = atomicAdd(&cur[cc >> BSH], 1);
        stage[p] = (rr << BSH) | (cc & (BNODES - 1));
    }
    __syncthreads();
    for (int i = t; i < cs; i += 512) temp[start + i] = stage[i];
}

// exclusive scan of bucket totals -> base (carry loop); sentinels.
__global__ void k_base(const int* __restrict__ tot, int* __restrict__ base,
                       int* __restrict__ ptrS, int E, int nb, int N) {
    __shared__ int s[512];
    __shared__ int carry;
    int t = threadIdx.x;
    if (t == 0) carry = 0;
    __syncthreads();
    for (int b0 = 0; b0 < nb; b0 += 512) {
        int i = b0 + t;
        int v = (i < nb) ? tot[i] : 0;
        s[t] = v;
        __syncthreads();
        for (int o = 1; o < 512; o <<= 1) {
            int x = (t >= o) ? s[t - o] : 0;
            __syncthreads();
            s[t] += x;
            __syncthreads();
        }
        if (i < nb) base[i] = s[t] - v + carry;
        __syncthreads();
        if (t == 0) carry += s[511];
        __syncthreads();
    }
    if (t == 0) { base[nb] = E; ptrS[N] = E; }
}

// Phase 2: one block per 256-node bucket. Deterministic per-cell bases via a
// 512-wide scan of cell lengths; wave-per-cell COALESCED load of temp into LDS
// raw[] (temp read once); histogram+scatter run out of LDS; csr written back
// fully coalesced. Overflow beyond RAWCAP spills via deterministic global path.
__global__ __launch_bounds__(512) void k_build(
                        const int* __restrict__ temp, const unsigned short* __restrict__ off,
                        const int* __restrict__ base, int* __restrict__ ptrS,
                        float* __restrict__ dinv, int* __restrict__ csr,
                        int NBLK, int N) {
    __shared__ int cnt[BNODES];
    __shared__ int cur[BNODES];
    __shared__ int sc[BNODES];
    __shared__ int cellstart[MAXCELL];
    __shared__ int raw[RAWCAP];
    __shared__ int stage[RAWCAP];
    int b = blockIdx.x;
    int t = threadIdx.x;     // 512 threads = 8 waves
    int wid = t >> 6, lane = t & 63;
    if (t < BNODES) cnt[t] = 0;
    // Phase 0: cell lengths + exclusive scan (coalesced ushort reads)
    int len0 = 0;
    if (t < NBLK) len0 = (int)off[(b + 1) * NBLK + t] - (int)off[b * NBLK + t];
    cellstart[t] = len0;
    __syncthreads();
    for (int o = 1; o < 512; o <<= 1) {
        int x = (t >= o) ? cellstart[t - o] : 0;
        __syncthreads();
        cellstart[t] += x;
        __syncthreads();
    }
    int incl = cellstart[t];
    __syncthreads();
    cellstart[t] = incl - len0;   // exclusive
    __syncthreads();
    // Phase A: wave-per-cell coalesced load into raw (overflow -> histogram direct)
    for (int cell = wid; cell < NBLK; cell += 8) {
        int s0 = off[b * NBLK + cell];
        int s1 = off[(b + 1) * NBLK + cell];
        int len = s1 - s0;
        int rb = cellstart[cell];
        const int* src = temp + cell * CHUNK + s0;
        for (int j = lane; j < len; j += 64) {
            int e = src[j];
            int idx = rb + j;
            if (idx < RAWCAP) raw[idx] = e;
            else atomicAdd(&cnt[e & (BNODES - 1)], 1);
        }
    }
    __syncthreads();
    // Phase B: histogram from LDS
    int total = base[b + 1] - base[b];
    int cap = total > RAWCAP ? RAWCAP : total;
    for (int i = t; i < cap; i += 512) atomicAdd(&cnt[raw[i] & (BNODES - 1)], 1);
    __syncthreads();
    // per-node exclusive scan (256 wide)
    if (t < BNODES) sc[t] = cnt[t];
    __syncthreads();
    for (int o = 1; o < BNODES; o <<= 1) {
        int x = 0;
        if (t < BNODES && t >= o) x = sc[t - o];
        __syncthreads();
        if (t < BNODES) sc[t] += x;
        __syncthreads();
    }
    int bb = base[b];
    if (t < BNODES) {
        int c = cnt[t];
        int lstart = sc[t] - c;            // local start within bucket
        int node = (b << BSH) + t;
        if (node < N) {
            ptrS[node] = bb + lstart;
            dinv[node] = rsqrtf(1.0f + (float)c);
        }
        cur[t] = lstart;
    }
    __syncthreads();
    // Phase C: scatter from LDS raw into LDS stage (local positions)
    for (int i = t; i < cap; i += 512) {
        int e = raw[i];
        int p = atomicAdd(&cur[e & (BNODES - 1)], 1);
        int r = e >> BSH;
        if (p < RAWCAP) stage[p] = r;
        else            csr[bb + p] = r;   // statistically unreachable
    }
    if (total > RAWCAP) {                  // statistically unreachable spill
        for (int cell = wid; cell < NBLK; cell += 8) {
            int s0 = off[b * NBLK + cell];
            int s1 = off[(b + 1) * NBLK + cell];
            int len = s1 - s0;
            int rb = cellstart[cell];
            const int* src = temp + cell * CHUNK + s0;
            for (int j = lane; j < len; j += 64) {
                if (rb + j >= RAWCAP) {
                    int e = src[j];
                    int p = atomicAdd(&cur[e & (BNODES - 1)], 1);
                    int r = e >> BSH;
                    if (p < RAWCAP) stage[p] = r;
                    else            csr[bb + p] = r;
                }
            }
        }
    }
    __syncthreads();
    // Phase D: coalesced writeback
    for (int i = t; i < cap; i += 512) csr[bb + i] = stage[i];
}

// h0h[v][k] = fp16( dinv[v] * (x @ W1)[v][k] )   (premultiplied, fp16 table)
__global__ void k_xw1(const float* __restrict__ x, const float* __restrict__ W1,
                      const float* __restrict__ dinv, _Float16* __restrict__ h0h, int N) {
    int t = blockIdx.x * blockDim.x + threadIdx.x;
    if (t >= N * 16) return;
    int v = t >> 4, k = t & 15;
    float x0 = x[v * 3 + 0], x1 = x[v * 3 + 1], x2 = x[v * 3 + 2];
    h0h[t] = (_Float16)(dinv[v] * (x0 * W1[k] + x1 * W1[16 + k] + x2 * W1[32 + k]));
}

// layer 1 gather over fp16 table (32B/row, L2-resident) + relu + W2 via shfl.
// Accumulation in f32. Writes h1h = fp16( dinv[v] * (h1 @ W2) ).
__global__ void k_gather1(const int* __restrict__ ptrS, const int* __restrict__ csr,
                          const float* __restrict__ dinv, const _Float16* __restrict__ h0h,
                          const float* __restrict__ W2, const float* __restrict__ b1,
                          _Float16* __restrict__ h1h, int N) {
    __shared__ float sW[256];
    sW[threadIdx.x] = W2[threadIdx.x];
    __syncthreads();
    int t = blockIdx.x * blockDim.x + threadIdx.x;
    int v = t >> 4, k = t & 15;
    if (v < N) {
        int s = ptrS[v], e = ptrS[v + 1];
        float a0 = 0.0f, a1 = 0.0f, a2 = 0.0f, a3 = 0.0f;
        int i = s;
        for (; i + 3 < e; i += 4) {
            int r0 = csr[i], r1 = csr[i + 1], r2 = csr[i + 2], r3 = csr[i + 3];
            a0 += (float)h0h[r0 * 16 + k];
            a1 += (float)h0h[r1 * 16 + k];
            a2 += (float)h0h[r2 * 16 + k];
            a3 += (float)h0h[r3 * 16 + k];
        }
        for (; i < e; ++i) a0 += (float)h0h[csr[i] * 16 + k];
        float d = dinv[v];
        float h = fmaxf(d * ((a0 + a1) + (a2 + a3) + (float)h0h[v * 16 + k]) + b1[k], 0.0f);
        float o = 0.0f;
#pragma unroll
        for (int j = 0; j < 16; ++j) o += __shfl(h, j, 16) * sW[j * 16 + k];
        h1h[v * 16 + k] = (_Float16)(d * o);
    }
}

// layer 2 gather over fp16 table + bias + pool with wave-level pre-reduction.
__global__ void k_gather2(const int* __restrict__ ptrS, const int* __restrict__ csr,
                          const float* __restrict__ dinv, const _Float16* __restrict__ h1h,
                          const float* __restrict__ b2, const int* __restrict__ batch,
                          float* __restrict__ g, int N) {
    int t = blockIdx.x * blockDim.x + threadIdx.x;
    int v = t >> 4, k = t & 15;
    bool valid = (v < N);
    float val = 0.0f;
    int bg = 0;
    if (valid) {
        int s = ptrS[v], e = ptrS[v + 1];
        float a0 = 0.0f, a1 = 0.0f, a2 = 0.0f, a3 = 0.0f;
        int i = s;
        for (; i + 3 < e; i += 4) {
            int r0 = csr[i], r1 = csr[i + 1], r2 = csr[i + 2], r3 = csr[i + 3];
            a0 += (float)h1h[r0 * 16 + k];
            a1 += (float)h1h[r1 * 16 + k];
            a2 += (float)h1h[r2 * 16 + k];
            a3 += (float)h1h[r3 * 16 + k];
        }
        for (; i < e; ++i) a0 += (float)h1h[csr[i] * 16 + k];
        float d = dinv[v];
        val = d * ((a0 + a1) + (a2 + a3) + (float)h1h[v * 16 + k]) + b2[k];
        bg = batch[v];
    }
    int lane = threadIdx.x & 63;
    int bg0 = __shfl(bg, lane & 15, 64);
    bool uni = __all(valid && (bg == bg0));
    if (uni) {
        val += __shfl_xor(val, 16, 64);
        val += __shfl_xor(val, 32, 64);
        if (lane < 16) atomicAdd(&g[bg * 16 + k], val);
    } else if (valid) {
        atomicAdd(&g[bg * 16 + k], val);
    }
}

// logits = g @ Wl + bl (16x7), then log_softmax over 7. One thread per graph.
__global__ void k_head(const float* __restrict__ g, const float* __restrict__ Wl,
                       const float* __restrict__ bl, float* __restrict__ out, int G) {
    int gi = blockIdx.x * blockDim.x + threadIdx.x;
    if (gi >= G) return;
    float gv[16];
#pragma unroll
    for (int k = 0; k < 16; ++k) gv[k] = g[gi * 16 + k];
    float lo[7];
    float mx = -1e30f;
#pragma unroll
    for (int j = 0; j < 7; ++j) {
        float a = bl[j];
#pragma unroll
        for (int k = 0; k < 16; ++k) a += gv[k] * Wl[k * 7 + j];
        lo[j] = a;
        mx = fmaxf(mx, a);
    }
    float s = 0.0f;
#pragma unroll
    for (int j = 0; j < 7; ++j) s += expf(lo[j] - mx);
    float lse = mx + logf(s);
#pragma unroll
    for (int j = 0; j < 7; ++j) out[gi * 7 + j] = lo[j] - lse;
}

extern "C" void kernel_launch(void* const* d_in, const int* in_sizes, int n_in,
                              void* d_out, int out_size, void* d_ws, size_t ws_size,
                              hipStream_t stream) {
    const float* x    = (const float*)d_in[0];
    const int*   ei   = (const int*)d_in[1];   // [2, E]: row = ei[0:E), col = ei[E:2E)
    const int*   batch = (const int*)d_in[3];
    const float* W1 = (const float*)d_in[4];
    const float* b1 = (const float*)d_in[5];
    const float* W2 = (const float*)d_in[6];
    const float* b2 = (const float*)d_in[7];
    const float* Wl = (const float*)d_in[8];
    const float* bl = (const float*)d_in[9];
    float* out = (float*)d_out;

    const int N = in_sizes[0] / 3;
    const int E = in_sizes[1] / 2;
    const int G = out_size / 7;

    const int* row = ei;
    const int* col = ei + E;

    const int NBLK = (E + CHUNK - 1) / CHUNK;   // must be <= MAXCELL (E <= 4.19M)
    const int nb   = (N + BNODES - 1) >> BSH;

    int* w = (int*)d_ws;
    float* dinv = (float*)w;            w += N;
    int*   ptrS = w;                    w += N + 1;
    int*   tot  = w;                    w += nb;
    int*   base = w;                    w += nb + 1;
    unsigned short* off = (unsigned short*)w;
    w += ((nb + 1) * NBLK + 1) / 2;     // ushort table, rounded up to int units
    int*   csr  = w;                    w += E;
    int tempsz = E > 32 * N ? E : 32 * N;
    int*   temp = w;                    w += tempsz;
    // fp16 feature tables alias temp (dead after k_build)
    _Float16* h0h = (_Float16*)temp;             // 16N halves = 8N ints
    _Float16* h1h = (_Float16*)(temp + 8 * N);   // 16N halves = 8N ints
    float* g    = (float*)w;            w += 16 * G;

    const int TB = 256;
    const int n16 = N * 16;
    const int G16 = G * 16;
    const int initn = (G16 > nb) ? G16 : nb;

    k_init<<<(initn + TB - 1) / TB, TB, 0, stream>>>(tot, g, nb, G16);
    k_bin<<<NBLK, 512, 0, stream>>>(row, col, temp, off, tot, E, NBLK, nb);
    k_base<<<1, 512, 0, stream>>>(tot, base, ptrS, E, nb, N);
    k_build<<<nb, 512, 0, stream>>>(temp, off, base, ptrS, dinv, csr, NBLK, N);
    k_xw1<<<(n16 + TB - 1) / TB, TB, 0, stream>>>(x, W1, dinv, h0h, N);
    k_gather1<<<(n16 + TB - 1) / TB, TB, 0, stream>>>(ptrS, csr, dinv, h0h, W2, b1, h1h, N);
    k_gather2<<<(n16 + TB - 1) / TB, TB, 0, stream>>>(ptrS, csr, dinv, h1h, b2, batch, g, N);
    k_head<<<(G + TB - 1) / TB, TB, 0, stream>>>(g, Wl, bl, out, G);
}